// Round 2
// 18570.552 us; speedup vs baseline: 1.0689x; 1.0689x over previous
//
#include <hip/hip_runtime.h>
#include <hip/hip_bf16.h>

// LSTM_19902878449909: persistent fused recurrent kernel for MI355X. R4.
// R3 failed to LINK: xproj fp32 (2 GB) pushed .bss past the 2 GiB PC32
// relocation limit. R4 stores xproj as fp16 (1 GB, total .bss ~1.55 GB).
// fp16 rel-err 2^-11 on |preact|<~6 is ~5e-4 abs -- far below the bf16
// h-rounding already in the data path.
// Structure vs R2:
//  (1) x-projection hoisted OUT of the recurrent loop into a pre-phase inside
//      the same kernel: Wi slice lives in LDS (loaded once), all 1024 steps'
//      xpart computed at MFMA rate, stored fp16 in frag-order to scratch.
//      Each WG reads back only its OWN blocks -> plain loads, no coherence
//      cost, prefetched before the poll.
//  (2) arrival sync: per-WG flag WORDS (64 independent stores per rb-group)
//      replace the 64-way same-line atomic RMW counter; every wave polls with
//      one coalesced 64-lane agent load + __all().
//  (3) all 4 waves run the recurrent GEMM (wave = (row-half, col-half)).

typedef __attribute__((ext_vector_type(8))) short short8;     // 8 bf16 = 4 VGPRs (MFMA A/B frag)
typedef __attribute__((ext_vector_type(4))) float floatx4;    // MFMA C/D frag
typedef __attribute__((ext_vector_type(4))) unsigned int uint4v;
typedef __attribute__((ext_vector_type(4))) _Float16 half4;   // 4 fp16 = 8 B
typedef unsigned long long u64;
typedef unsigned short u16;

#define NB 128
#define NTT 1024

// Device-global scratch (BSS, total ~1.55 GB < 2 GiB PC32 limit).
__device__ __attribute__((aligned(256))) u16 g_xpack[(size_t)NTT * NB * 1024]; // [t][b][k] bf16, 256 MB
__device__ __attribute__((aligned(256))) u16 g_wpack[2][4194304];              // [mat(i/h)][cb][ks][nt][lane*8], 8 MB each
__device__ __attribute__((aligned(256))) u16 g_hall[NTT][NB * 1024];           // write-once h per step, 256 MB
__device__ __attribute__((aligned(256))) u16 g_xproj[(size_t)NTT * 256 * 2048]; // xproj fp16, frag order, 1 GB
__device__ __attribute__((aligned(256))) unsigned g_flags[256];                // [rb][cb] step-complete flags

__device__ __forceinline__ u16 f2bf(float f) {   // fp32 -> bf16 RNE
  unsigned u = __float_as_uint(f);
  u += 0x7FFFu + ((u >> 16) & 1u);
  return (u16)(u >> 16);
}

// ---- pack weights into B-fragment order ------------------------------------
// B-frag (mfma_f32_16x16x32_bf16): lane l holds B[k = ks*32 + (l>>4)*8 + j][n = l&15].
// Column list per cb (64 gate cols): nt0=[i|f]@hc0, nt1=[g|o]@hc0, nt2=[i|f]@hc1, nt3=[g|o]@hc1
// with hc(wn) = cb*16 + wn*8; n<8 -> first seg, n>=8 -> second seg.
__global__ void pack_w(const float* __restrict__ Wii, const float* __restrict__ Wif,
                       const float* __restrict__ Wig, const float* __restrict__ Wio,
                       const float* __restrict__ Whi, const float* __restrict__ Whf,
                       const float* __restrict__ Whg, const float* __restrict__ Who) {
  int wid = (blockIdx.x << 2) | (threadIdx.x >> 6);  // 0..16383
  int lane = threadIdx.x & 63;
  int mat = wid >> 13;          // 0 = Wi, 1 = Wh
  int rem = wid & 8191;
  int cb = rem >> 7;
  int ks = (rem >> 2) & 31;
  int nt = rem & 3;
  int n = lane & 15, quad = lane >> 4;
  const float *Wlo, *Whi2;
  if (mat == 0) { Wlo = (nt & 1) ? Wig : Wii; Whi2 = (nt & 1) ? Wio : Wif; }
  else          { Wlo = (nt & 1) ? Whg : Whi; Whi2 = (nt & 1) ? Who : Whf; }
  const float* src = (n < 8) ? Wlo : Whi2;
  int col = (cb << 4) + ((nt >> 1) << 3) + (n & 7);
  int k0 = (ks << 5) + (quad << 3);
  u16 tmp[8];
#pragma unroll
  for (int j = 0; j < 8; ++j) tmp[j] = f2bf(src[(size_t)(k0 + j) * 1024 + col]);
  *(uint4v*)&g_wpack[mat][((size_t)((cb * 32 + ks) * 4 + nt) << 9) + lane * 8] = *(uint4v*)tmp;
}

// ---- pack x: [b][t][k] fp32 -> [t][b][k] bf16; zero g_hall[0] / flags ------
__global__ void pack_x(const float* __restrict__ x) {
  int pair = threadIdx.x >> 7;            // 2 (b,t) pairs per 256-thread block
  int kt = (threadIdx.x & 127) << 3;      // 8 elements per thread
  int bt = (blockIdx.x << 1) | pair;      // 0..131071
  int b = bt >> 10, t = bt & 1023;
  const float* src = x + ((size_t)b * 1024 + t) * 1024 + kt;
  u16 tmp[8];
#pragma unroll
  for (int j = 0; j < 8; ++j) tmp[j] = f2bf(src[j]);
  *(uint4v*)&g_xpack[((size_t)t * NB + b) * 1024 + kt] = *(uint4v*)tmp;
  if (bt < 128) {  // zero g_hall[0]: 131072 u16 = 128 * 128 threads * 8
    size_t base = ((size_t)bt << 10) + ((size_t)(threadIdx.x & 127) << 3);
    uint4v z = {0u, 0u, 0u, 0u};
    *(uint4v*)&g_hall[0][base] = z;
  }
  if (blockIdx.x == 0) g_flags[threadIdx.x] = 0u;
}

// ---- main persistent kernel ------------------------------------------------
__global__ __launch_bounds__(256, 1) void lstm_main(
    const float* __restrict__ bi, const float* __restrict__ bf,
    const float* __restrict__ bg, const float* __restrict__ bo,
    float* __restrict__ out) {
  __shared__ u16 whlds[65536];         // 128 KB: Wi slice in phase 1, Wh slice in phase 3

  const int tid = threadIdx.x;
  const int wave = tid >> 6, lane = tid & 63;
  const int wg = blockIdx.x;
  const int xcd = wg & 7;                    // blocks round-robin over 8 XCDs
  const int rb = xcd & 3;                    // one row-block per XCD (h L2 reuse)
  const int cb = ((xcd >> 2) << 5) | (wg >> 3);  // contiguous 512-col range per XCD
  const int rowbase = rb << 5;
  const int n = lane & 15, quad = lane >> 4;

  // ---- phase 0: Wi slice -> LDS (packed layout == global layout) -----------
  {
    const u16* src = &g_wpack[0][(size_t)cb << 16];
#pragma unroll 4
    for (int i = 0; i < 32; ++i) {
      int off = ((i << 8) + tid) << 3;
      *(uint4v*)&whlds[off] = *(const uint4v*)&src[off];
    }
  }
  __syncthreads();

  // ---- phase 1: xproj(t) = bias + x_t @ Wi for ALL t, stored frag-order ----
  // waves: (pwn = col-half, tpar = t parity); each wave does 512 steps.
  {
    const int pwn = wave & 1, tpar = wave >> 1;
    const int pcolb = (cb << 4) | (pwn << 3) | (n & 7);
    const float pb0 = (n < 8) ? bi[pcolb] : bf[pcolb];   // tile0 = [i|f]
    const float pb1 = (n < 8) ? bg[pcolb] : bo[pcolb];   // tile1 = [g|o]
    for (int t = tpar; t < NTT; t += 2) {
      const u16* xp = &g_xpack[((size_t)t * NB + rowbase) << 10];
      floatx4 acc[2][2];
#pragma unroll
      for (int m = 0; m < 2; ++m) {
        acc[m][0] = floatx4{pb0, pb0, pb0, pb0};
        acc[m][1] = floatx4{pb1, pb1, pb1, pb1};
      }
      short8 A[2][2][4];   // 4-kstep chunks, double-buffered
#pragma unroll
      for (int j = 0; j < 4; ++j)
#pragma unroll
        for (int m = 0; m < 2; ++m)
          A[0][m][j] = *(const short8*)&xp[(((m << 4) | n) << 10) + (j << 5) + (quad << 3)];
#pragma unroll
      for (int c = 0; c < 8; ++c) {
        int cur = c & 1, nxt = cur ^ 1;
        if (c < 7) {
#pragma unroll
          for (int j = 0; j < 4; ++j) {
            int ks = ((c + 1) << 2) | j;
#pragma unroll
            for (int m = 0; m < 2; ++m)
              A[nxt][m][j] =
                  *(const short8*)&xp[(((m << 4) | n) << 10) + (ks << 5) + (quad << 3)];
          }
        }
#pragma unroll
        for (int j = 0; j < 4; ++j) {
          int ks = (c << 2) | j;
          short8 b0 = *(const short8*)&whlds[(((ks << 2) | (pwn << 1)) << 9) + (lane << 3)];
          short8 b1 = *(const short8*)&whlds[(((ks << 2) | (pwn << 1) | 1) << 9) + (lane << 3)];
#pragma unroll
          for (int m = 0; m < 2; ++m) {
            acc[m][0] = __builtin_amdgcn_mfma_f32_16x16x32_bf16(A[cur][m][j], b0, acc[m][0], 0, 0, 0);
            acc[m][1] = __builtin_amdgcn_mfma_f32_16x16x32_bf16(A[cur][m][j], b1, acc[m][1], 0, 0, 0);
          }
        }
      }
      // frag-order fp16 store: elem off = t8*256 + quad*64 + n*4, t8 = ((m*2+pwn)*2)|q
      u16* dst = &g_xproj[(((size_t)t << 8) + (rb << 6) + cb) << 11];
#pragma unroll
      for (int m = 0; m < 2; ++m)
#pragma unroll
        for (int q = 0; q < 2; ++q) {
          int t8 = (((m << 1) | pwn) << 1) | q;
          half4 hv;
#pragma unroll
          for (int r = 0; r < 4; ++r) hv[r] = (_Float16)acc[m][q][r];
          *(half4*)&dst[(t8 << 8) + (quad << 6) + (n << 2)] = hv;
        }
    }
  }
  __syncthreads();   // includes vmcnt(0): phase-1 stores drained before LDS reuse

  // ---- phase 2: Wh slice -> LDS (overwrites Wi) -----------------------------
  {
    const u16* src = &g_wpack[1][(size_t)cb << 16];
#pragma unroll 4
    for (int i = 0; i < 32; ++i) {
      int off = ((i << 8) + tid) << 3;
      *(uint4v*)&whlds[off] = *(const uint4v*)&src[off];
    }
  }
  __syncthreads();

  // ---- phase 3: recurrence. wave = (cwm = row-half, cwn = col-half) ---------
  const int cwm = wave >> 1, cwn = wave & 1;
  const int colbase = (cb << 4) | (cwn << 3);
  float creg[4] = {0.f, 0.f, 0.f, 0.f};   // cell state: row cwm*16+quad*4+r, col n&7
  unsigned* myflag = &g_flags[(rb << 6) | cb];
  unsigned* rbflags = &g_flags[rb << 6];

  for (int t = 0; t < NTT; ++t) {
    // xpart prefetch: own-WG data, ready since phase 1 -> completes during poll
    const u16* xsrc = &g_xproj[(((size_t)t << 8) + (rb << 6) + cb) << 11];
    half4 xh0 = *(const half4*)&xsrc[((((cwm << 1) | cwn) << 1) << 8) + (quad << 6) + (n << 2)];
    half4 xh1 =
        *(const half4*)&xsrc[(((((cwm << 1) | cwn) << 1) | 1) << 8) + (quad << 6) + (n << 2)];

    if (t > 0) {
      // per-wave independent poll: one coalesced 64-lane agent load per probe
      int guard = 0;
      for (;;) {
        unsigned v = __hip_atomic_load(&rbflags[lane], __ATOMIC_RELAXED, __HIP_MEMORY_SCOPE_AGENT);
        if (__all((int)(v >= (unsigned)t))) break;
        __builtin_amdgcn_s_sleep(2);
        if (++guard > (1 << 20)) break;   // deadlock -> wrong answer, not hang
      }
    }
    asm volatile("" ::: "memory");   // no g_hall load hoisting above the wait

    // h(t-1) GEMM: A = my 16 rows of g_hall[t], B = Wh slice in LDS
    const u16* hp = &g_hall[t][(rowbase + (cwm << 4)) << 10];
    floatx4 acc0, acc1;
#pragma unroll
    for (int r = 0; r < 4; ++r) { acc0[r] = (float)xh0[r]; acc1[r] = (float)xh1[r]; }
    short8 A[2][8];   // 8-kstep chunks, double-buffered
#pragma unroll
    for (int j = 0; j < 8; ++j)
      A[0][j] = *(const short8*)&hp[(n << 10) + (j << 5) + (quad << 3)];
#pragma unroll
    for (int c = 0; c < 4; ++c) {
      int cur = c & 1, nxt = cur ^ 1;
      if (c < 3) {
#pragma unroll
        for (int j = 0; j < 8; ++j) {
          int ks = ((c + 1) << 3) | j;
          A[nxt][j] = *(const short8*)&hp[(n << 10) + (ks << 5) + (quad << 3)];
        }
      }
#pragma unroll
      for (int j = 0; j < 8; ++j) {
        int ks = (c << 3) | j;
        short8 b0 = *(const short8*)&whlds[(((ks << 2) | (cwn << 1)) << 9) + (lane << 3)];
        short8 b1 = *(const short8*)&whlds[(((ks << 2) | (cwn << 1) | 1) << 9) + (lane << 3)];
        acc0 = __builtin_amdgcn_mfma_f32_16x16x32_bf16(A[cur][j], b0, acc0, 0, 0, 0);
        acc1 = __builtin_amdgcn_mfma_f32_16x16x32_bf16(A[cur][j], b1, acc1, 0, 0, 0);
      }
    }

    // -------- epilogue: gates, c update, h store -----------------------------
    // C/D layout: col = lane&15, row = quad*4 + r. tile0 = [i|f], tile1 = [g|o].
    u16* hw = (t < 1023) ? &g_hall[t + 1][0] : (u16*)0;
#pragma unroll
    for (int r = 0; r < 4; ++r) {
      float v0 = acc0[r], v1 = acc1[r];
      float q0 = __shfl_xor(v0, 8, 64);
      float q1 = __shfl_xor(v1, 8, 64);
      bool lo = (n < 8);
      float ipre = lo ? v0 : q0;
      float fpre = lo ? q0 : v0;
      float gpre = lo ? v1 : q1;
      float opre = lo ? q1 : v1;
      float iv = 1.f / (1.f + __expf(-ipre));
      float fv = 1.f / (1.f + __expf(-fpre));
      float eg = __expf(2.f * gpre);
      float gv = 1.f - 2.f / (eg + 1.f);       // tanh
      float ov = 1.f / (1.f + __expf(-opre));
      float cn = fv * creg[r] + iv * gv;
      creg[r] = cn;
      float ec = __expf(2.f * cn);
      float tc = 1.f - 2.f / (ec + 1.f);       // tanh(c)
      float hn = ov * tc;
      int row = rowbase + (cwm << 4) + (quad << 2) + r;
      if (t < 1023) {
        unsigned hv = (unsigned)f2bf(hn);
        unsigned u01 = (hv & 0xFFFFu) | (((unsigned)__shfl_xor((int)hv, 1, 64)) << 16);
        unsigned u23 = (unsigned)__shfl_xor((int)u01, 2, 64);
        if (lo && (n & 3) == 0) {   // lanes n in {0,4}: one 8B store of 4 bf16
          u64 pk = (u64)u01 | ((u64)u23 << 32);
          __hip_atomic_store((u64*)&hw[(row << 10) + colbase + n], pk,
                             __ATOMIC_RELAXED, __HIP_MEMORY_SCOPE_AGENT);
        }
      } else if (lo) {              // final step: fp32 h and c to d_out
        int col = colbase | n;
        out[(row << 10) + col] = hn;
        out[131072 + (row << 10) + col] = cn;
      }
    }
    asm volatile("" ::: "memory");
    __builtin_amdgcn_s_waitcnt(0);   // my h stores drained (at MALL) ...
    __syncthreads();                 // ... for ALL 4 waves of this WG ...
    if (tid == 0 && t < 1023)        // ... then one independent flag WORD store
      __hip_atomic_store(myflag, (unsigned)(t + 1), __ATOMIC_RELAXED, __HIP_MEMORY_SCOPE_AGENT);
  }
}

extern "C" void kernel_launch(void* const* d_in, const int* in_sizes, int n_in,
                              void* d_out, int out_size, void* d_ws, size_t ws_size,
                              hipStream_t stream) {
  const float* x   = (const float*)d_in[0];
  const float* Wii = (const float*)d_in[1];
  const float* Wif = (const float*)d_in[2];
  const float* Wig = (const float*)d_in[3];
  const float* Wio = (const float*)d_in[4];
  const float* Whi = (const float*)d_in[5];
  const float* Whf = (const float*)d_in[6];
  const float* Whg = (const float*)d_in[7];
  const float* Who = (const float*)d_in[8];
  const float* bi  = (const float*)d_in[9];
  const float* bf_ = (const float*)d_in[10];
  const float* bg  = (const float*)d_in[11];
  const float* bo  = (const float*)d_in[12];
  float* out = (float*)d_out;

  pack_w<<<4096, 256, 0, stream>>>(Wii, Wif, Wig, Wio, Whi, Whf, Whg, Who);
  pack_x<<<65536, 256, 0, stream>>>(x);
  lstm_main<<<256, 256, 0, stream>>>(bi, bf_, bg, bo, out);
}